// Round 3
// baseline (953.405 us; speedup 1.0000x reference)
//
#include <hip/hip_runtime.h>
#include <hip/hip_cooperative_groups.h>
#include <hip/hip_bf16.h>
#include <math.h>

// GAT x3 + LayerNorm for MI355X (gfx950).
// R14: ALL seven dispatches (memset + k1 + agg0 + gemm1 + agg4 + gemm2 +
// agg_ln) fused into ONE cooperative kernel with grid.sync() phase barriers.
// Eliminates 6 launch/drain boundaries + the memset dispatch. Grid sized via
// occupancy query; __launch_bounds__(256,4) caps VGPR at 128 (>=4 blocks/CU
// co-resident). GEMM phase uses single-tile inner loop to fit the register
// cap. __threadfence() brackets each sync for cross-XCD visibility.
// Carried (R12/R13): bucketed scatter CSR (CAP=64), inline softmax weights
// in aggs, easum-based analytic self-loop (no asum atomics), bf16 h,
// al = A @ va via extra MFMA col-tile, layer-0 aggregate-then-project,
// scalar-path (s_load) edge-record reads.

namespace cg = cooperative_groups;

typedef __attribute__((ext_vector_type(8))) short short8;
typedef __attribute__((ext_vector_type(4))) float float4v;

#define CAP 64

__device__ __forceinline__ float wave_sum(float v) {
#pragma unroll
  for (int off = 32; off > 0; off >>= 1) v += __shfl_xor(v, off, 64);
  return v;
}

__device__ __forceinline__ unsigned short f2bf(float v) {
  unsigned u = __float_as_uint(v);
  unsigned r = u + 0x7fff + ((u >> 16) & 1);  // RNE
  return (unsigned short)(r >> 16);
}

__device__ __forceinline__ float bf2f(unsigned short u) {
  return __uint_as_float(((unsigned)u) << 16);
}

// single-tile MFMA GEMM strip (16 rows, K=256): bf16 out; al_s/al_d from the
// extra va col-tile. Single-tile inner loop keeps VGPR under the 128 cap.
template <int M, int H>
__device__ __forceinline__ void gemm_strip(
    int strip, const unsigned short* __restrict__ Abf,
    const unsigned short* __restrict__ Wfrag, unsigned short* __restrict__ out,
    float* __restrict__ al_s, float* __restrict__ al_d, int n, int lane) {
  int row0 = strip * 16;
  int m = lane & 15, q = lane >> 4;

  short8 afrag[8];
  int r = row0 + m;
  if (r < n) {
    const short8* arow = (const short8*)(Abf + (size_t)r * 256);
#pragma unroll
    for (int ks = 0; ks < 8; ks++) afrag[ks] = arow[ks * 4 + q];
  } else {
#pragma unroll
    for (int ks = 0; ks < 8; ks++) afrag[ks] = (short8)0;
  }

  const short8* wf = (const short8*)Wfrag;

#pragma unroll 1
  for (int nt = 0; nt < M / 16; nt++) {
    const short8* bl = wf + (size_t)nt * 8 * 64 + lane;
    short8 bf[8];
#pragma unroll
    for (int ks = 0; ks < 8; ks++) bf[ks] = bl[ks * 64];
    float4v acc = {0.f, 0.f, 0.f, 0.f};
#pragma unroll
    for (int ks = 0; ks < 8; ks++)
      acc = __builtin_amdgcn_mfma_f32_16x16x32_bf16(afrag[ks], bf[ks], acc, 0, 0, 0);
    int col = nt * 16 + m;
#pragma unroll
    for (int reg = 0; reg < 4; reg++) {
      int rr = row0 + q * 4 + reg;
      if (rr < n) out[(size_t)rr * M + col] = f2bf(acc[reg]);
    }
  }

  {  // va col-tile -> al_s / al_d
    const short8* bl = wf + (size_t)(M / 16) * 8 * 64 + lane;
    short8 bf[8];
#pragma unroll
    for (int ks = 0; ks < 8; ks++) bf[ks] = bl[ks * 64];
    float4v acc = {0.f, 0.f, 0.f, 0.f};
#pragma unroll
    for (int ks = 0; ks < 8; ks++)
      acc = __builtin_amdgcn_mfma_f32_16x16x32_bf16(afrag[ks], bf[ks], acc, 0, 0, 0);
#pragma unroll
    for (int reg = 0; reg < 4; reg++) {
      int rr = row0 + q * 4 + reg;
      if (rr < n) {
        if (m < H) al_s[(size_t)rr * H + m] = acc[reg];
        else if (m < 2 * H) al_d[(size_t)rr * H + (m - H)] = acc[reg];
      }
    }
  }
}

__global__ __launch_bounds__(256, 4) void mega_kernel(
    const float* __restrict__ x, const int* __restrict__ srcv,
    const int* __restrict__ dstv, const float* __restrict__ eattr,
    const float* __restrict__ W0, const float* __restrict__ as0,
    const float* __restrict__ ad0, const float* __restrict__ We0,
    const float* __restrict__ ae0, const float* __restrict__ b0,
    const float* __restrict__ W1, const float* __restrict__ as1,
    const float* __restrict__ ad1, const float* __restrict__ We1,
    const float* __restrict__ ae1, const float* __restrict__ b1,
    const float* __restrict__ W2, const float* __restrict__ as2,
    const float* __restrict__ ad2, const float* __restrict__ We2,
    const float* __restrict__ ae2, const float* __restrict__ b2,
    const float* __restrict__ lng, const float* __restrict__ lnb,
    unsigned short* __restrict__ Wf1, unsigned short* __restrict__ Wf2,
    float* __restrict__ wedot, float* __restrict__ al_s, float* __restrict__ al_d,
    int* __restrict__ deg, int2* __restrict__ ebuf,
    unsigned short* __restrict__ bufA, unsigned short* __restrict__ bufB,
    float* __restrict__ outp, int N, int E) {
  cg::grid_group grid = cg::this_grid();
  int tid = threadIdx.x;
  int nb = gridDim.x;
  int lane = tid & 63;
  int gw = blockIdx.x * 4 + (tid >> 6);
  int nw = nb * 4;
  __shared__ float va[128];

  int gD = (N + 255) >> 8;

  // ================= P0: prep (Wf1/Wf2/wedot/al0-dots) + zero deg =========
  {
    int totalU = 353 + gD + gD;
    for (int u = blockIdx.x; u < totalU; u += nb) {
      if (u < 272) {  // Wf1: 16 W1-tiles + 1 va1 tile, bf16 fragment order
        int idx = u * 256 + tid;
        int j = idx & 7, ln = (idx >> 3) & 63, ks = (idx >> 9) & 7, nt = idx >> 12;
        int k = ks * 32 + (ln >> 4) * 8 + j;
        int col = ln & 15;
        float v = 0.f;
        if (nt < 16) {
          v = W1[(size_t)k * 256 + nt * 16 + col];
        } else if (col < 4) {
          for (int c = 0; c < 64; c++) v = fmaf(W1[(size_t)k * 256 + col * 64 + c], as1[col * 64 + c], v);
        } else if (col < 8) {
          int h = col - 4;
          for (int c = 0; c < 64; c++) v = fmaf(W1[(size_t)k * 256 + h * 64 + c], ad1[h * 64 + c], v);
        }
        Wf1[idx] = f2bf(v);
      } else if (u < 352) {  // Wf2: 4 W2-tiles + 1 va2 tile
        int idx = (u - 272) * 256 + tid;
        int j = idx & 7, ln = (idx >> 3) & 63, ks = (idx >> 9) & 7, nt = idx >> 12;
        int k = ks * 32 + (ln >> 4) * 8 + j;
        int col = ln & 15;
        float v = 0.f;
        if (nt < 4) {
          v = W2[(size_t)k * 64 + nt * 16 + col];
        } else if (col < 1) {
          for (int c = 0; c < 64; c++) v = fmaf(W2[(size_t)k * 64 + c], as2[c], v);
        } else if (col < 2) {
          for (int c = 0; c < 64; c++) v = fmaf(W2[(size_t)k * 64 + c], ad2[c], v);
        }
        Wf2[idx] = f2bf(v);
      } else if (u == 352) {  // wedot
        if (tid < 64) {
          int c = tid;
          for (int h = 0; h < 4; h++) {
            float v = wave_sum(We0[h * 64 + c] * ae0[h * 64 + c]);
            if (c == 0) wedot[h] = v;
          }
          for (int h = 0; h < 4; h++) {
            float v = wave_sum(We1[h * 64 + c] * ae1[h * 64 + c]);
            if (c == 0) wedot[4 + h] = v;
          }
          float v = wave_sum(We2[c] * ae2[c]);
          if (c == 0) wedot[8] = v;
        }
      } else if (u < 353 + gD) {  // layer-0 dots: al = x @ va0
        if (tid < 128) {
          int k = tid >> 3, col = tid & 7;
          float v = 0.f;
          if (col < 4) {
            for (int c = 0; c < 64; c++) v = fmaf(W0[(size_t)k * 256 + col * 64 + c], as0[col * 64 + c], v);
          } else {
            int h = col - 4;
            for (int c = 0; c < 64; c++) v = fmaf(W0[(size_t)k * 256 + h * 64 + c], ad0[h * 64 + c], v);
          }
          va[tid] = v;
        }
        __syncthreads();
        int node = (u - 353) * 256 + tid;
        if (node < N) {
          const float4* xr = (const float4*)(x + (size_t)node * 16);
          float4 xv[4];
#pragma unroll
          for (int qq = 0; qq < 4; qq++) xv[qq] = xr[qq];
          float al[8];
#pragma unroll
          for (int j = 0; j < 8; j++) al[j] = 0.f;
#pragma unroll
          for (int k = 0; k < 16; k++) {
            float xk = ((const float*)xv)[k];
#pragma unroll
            for (int j = 0; j < 8; j++) al[j] = fmaf(xk, va[k * 8 + j], al[j]);
          }
          ((float4*)al_s)[node] = make_float4(al[0], al[1], al[2], al[3]);
          ((float4*)al_d)[node] = make_float4(al[4], al[5], al[6], al[7]);
        }
        __syncthreads();
      } else {  // zero deg
        int idx = (u - 353 - gD) * 256 + tid;
        if (idx < N) deg[idx] = 0;
      }
    }
  }
  __threadfence();
  grid.sync();

  // ================= P1: degree count + bucket scatter =====================
  for (int e = blockIdx.x * 256 + tid; e < E; e += nb * 256) {
    int d = dstv[e];
    int s = srcv[e];
    float ea = eattr[e];
    int pos = atomicAdd(&deg[d], 1);
    if (pos < CAP) ebuf[(size_t)d * CAP + pos] = make_int2(s, __float_as_int(ea));
  }
  __threadfence();
  grid.sync();

  // ================= P2: layer-0 agg + project (inline weights) ============
  for (int node = gw; node < N; node += nw) {
    int es = lane >> 4;
    int c = lane & 15;
    int dg = deg[node];
    int cnt = dg < CAP ? dg : CAP;
    float xself = x[(size_t)node * 16 + c];
    float4 as4s = ((const float4*)al_s)[node];
    float4 ald = ((const float4*)al_d)[node];
    float wd[4];
#pragma unroll
    for (int h = 0; h < 4; h++) wd[h] = wedot[h];

    float Z[4] = {0.f, 0.f, 0.f, 0.f};
    float den[4] = {0.f, 0.f, 0.f, 0.f};
    float easum = 0.f;

    for (int i = 0; i < cnt; i += 4) {
      int base = __builtin_amdgcn_readfirstlane(node * CAP + i);
      int2 r0 = ebuf[base], r1 = ebuf[base + 1], r2 = ebuf[base + 2], r3 = ebuf[base + 3];
      int2 rm = (es == 0) ? r0 : (es == 1) ? r1 : (es == 2) ? r2 : r3;
      bool valid = (i + es) < cnt;
      int src = valid ? rm.x : 0;
      float ev = valid ? __int_as_float(rm.y) : 0.f;
      float xv = x[(size_t)src * 16 + c];
      float4 as4 = ((const float4*)al_s)[src];
      easum += ev;
#pragma unroll
      for (int h = 0; h < 4; h++) {
        float a = ((const float*)&as4)[h] + ((const float*)&ald)[h] + ev * wd[h];
        a = fmaxf(a, 0.2f * a);
        a = fminf(a, 30.f);
        float wv = __expf(a);
        wv = valid ? wv : 0.f;
        den[h] += wv;
        Z[h] = fmaf(wv, xv, Z[h]);
      }
    }

#pragma unroll
    for (int h = 0; h < 4; h++) {
      Z[h] += __shfl_xor(Z[h], 16, 64);
      Z[h] += __shfl_xor(Z[h], 32, 64);
      den[h] += __shfl_xor(den[h], 16, 64);
      den[h] += __shfl_xor(den[h], 32, 64);
    }
    easum += __shfl_xor(easum, 16, 64);
    easum += __shfl_xor(easum, 32, 64);

    {  // self loop post-reduce
      float evs = easum / fmaxf((float)dg, 1.f);
#pragma unroll
      for (int h = 0; h < 4; h++) {
        float a = ((const float*)&as4s)[h] + ((const float*)&ald)[h] + evs * wd[h];
        a = fmaxf(a, 0.2f * a);
        a = fminf(a, 30.f);
        float wv = __expf(a);
        den[h] += wv;
        Z[h] = fmaf(wv, xself, Z[h]);
      }
    }

    int h = es;
    float zsel = (h == 0) ? Z[0] : (h == 1) ? Z[1] : (h == 2) ? Z[2] : Z[3];
    float dsel = (h == 0) ? den[0] : (h == 1) ? den[1] : (h == 2) ? den[2] : den[3];
    float zn = zsel / (dsel + 1e-16f);
    float4 w0r[16];
#pragma unroll
    for (int cc = 0; cc < 16; cc++) w0r[cc] = ((const float4*)(W0 + (size_t)cc * 256))[lane];
    float zc[16];
    int basel = lane & 48;
#pragma unroll
    for (int cc = 0; cc < 16; cc++) zc[cc] = __shfl(zn, basel + cc, 64);
    float o[4];
    float4 b4 = ((const float4*)b0)[lane];
#pragma unroll
    for (int jj = 0; jj < 4; jj++) o[jj] = ((const float*)&b4)[jj];
#pragma unroll
    for (int cc = 0; cc < 16; cc++) {
#pragma unroll
      for (int jj = 0; jj < 4; jj++) o[jj] = fmaf(zc[cc], ((const float*)&w0r[cc])[jj], o[jj]);
    }
    ushort4 o4;
    float ox = o[0] > 0.f ? o[0] : expm1f(o[0]);
    float oy = o[1] > 0.f ? o[1] : expm1f(o[1]);
    float oz = o[2] > 0.f ? o[2] : expm1f(o[2]);
    float ow = o[3] > 0.f ? o[3] : expm1f(o[3]);
    o4.x = f2bf(ox);
    o4.y = f2bf(oy);
    o4.z = f2bf(oz);
    o4.w = f2bf(ow);
    ((ushort4*)bufA)[(size_t)node * 64 + lane] = o4;
  }
  __threadfence();
  grid.sync();

  // ================= P3: gemm1 (bufA -> bufB, al_s/al_d) ===================
  {
    int nStrip = (N + 15) >> 4;
    for (int sp = gw; sp < nStrip; sp += nw)
      gemm_strip<256, 4>(sp, bufA, Wf1, bufB, al_s, al_d, N, lane);
  }
  __threadfence();
  grid.sync();

  // ================= P4: layer-1 agg (bufB -> bufA) ========================
  for (int node = gw; node < N; node += nw) {
    int half = lane >> 5;
    int l = lane & 31;
    int h4 = l >> 3;
    int dg = deg[node];
    int cnt = dg < CAP ? dg : CAP;
    float aldh = al_d[(size_t)node * 4 + h4];
    float alsh = al_s[(size_t)node * 4 + h4];
    float wdh = wedot[4 + h4];
    short8 rowS = ((const short8*)(bufB + (size_t)node * 256))[l];

    float acc[8];
#pragma unroll
    for (int j = 0; j < 8; j++) acc[j] = 0.f;
    float den = 0.f;
    float easum = 0.f;

    for (int i = 0; i < cnt; i += 4) {
      int base = __builtin_amdgcn_readfirstlane(node * CAP + i);
      int2 r0 = ebuf[base], r1 = ebuf[base + 1], r2 = ebuf[base + 2], r3 = ebuf[base + 3];
      bool vA = (i + (half ? 1 : 0)) < cnt;
      bool vB = (i + (half ? 3 : 2)) < cnt;
      int2 rA = half ? r1 : r0;
      int2 rB = half ? r3 : r2;
      int srcA = vA ? rA.x : 0;
      int srcB = vB ? rB.x : 0;
      float evA = vA ? __int_as_float(rA.y) : 0.f;
      float evB = vB ? __int_as_float(rB.y) : 0.f;
      easum += evA + evB;
      float aA = al_s[(size_t)srcA * 4 + h4] + aldh + evA * wdh;
      float aB = al_s[(size_t)srcB * 4 + h4] + aldh + evB * wdh;
      aA = fmaxf(aA, 0.2f * aA);
      aB = fmaxf(aB, 0.2f * aB);
      aA = fminf(aA, 30.f);
      aB = fminf(aB, 30.f);
      float wA = __expf(aA);
      float wB = __expf(aB);
      wA = vA ? wA : 0.f;
      wB = vB ? wB : 0.f;
      short8 rowA = ((const short8*)(bufB + (size_t)srcA * 256))[l];
      short8 rowB = ((const short8*)(bufB + (size_t)srcB * 256))[l];
      den += wA + wB;
      const unsigned short* pa = (const unsigned short*)&rowA;
      const unsigned short* pb = (const unsigned short*)&rowB;
#pragma unroll
      for (int j = 0; j < 8; j++) acc[j] = fmaf(wA, bf2f(pa[j]), acc[j]);
#pragma unroll
      for (int j = 0; j < 8; j++) acc[j] = fmaf(wB, bf2f(pb[j]), acc[j]);
    }

    den += __shfl_xor(den, 32, 64);
    easum += __shfl_xor(easum, 32, 64);
#pragma unroll
    for (int j = 0; j < 8; j++) acc[j] += __shfl_xor(acc[j], 32, 64);

    {  // self loop post-reduce
      float evs = easum / fmaxf((float)dg, 1.f);
      float a = alsh + aldh + evs * wdh;
      a = fmaxf(a, 0.2f * a);
      a = fminf(a, 30.f);
      float wv = __expf(a);
      const unsigned short* ps = (const unsigned short*)&rowS;
      den += wv;
#pragma unroll
      for (int j = 0; j < 8; j++) acc[j] = fmaf(wv, bf2f(ps[j]), acc[j]);
    }

    if (half == 0) {
      float inv = 1.f / (den + 1e-16f);
      float4 bb0 = ((const float4*)b1)[l * 2];
      float4 bb1 = ((const float4*)b1)[l * 2 + 1];
      unsigned short o8[8];
#pragma unroll
      for (int j = 0; j < 8; j++) {
        float bjv = (j < 4) ? ((const float*)&bb0)[j] : ((const float*)&bb1)[j - 4];
        float o = acc[j] * inv + bjv;
        o = o > 0.f ? o : expm1f(o);
        o8[j] = f2bf(o);
      }
      ((short8*)(bufA + (size_t)node * 256))[l] = *(short8*)o8;
    }
  }
  __threadfence();
  grid.sync();

  // ================= P5: gemm2 (bufA -> bufB, al_s/al_d) ===================
  {
    int nStrip = (N + 15) >> 4;
    for (int sp = gw; sp < nStrip; sp += nw)
      gemm_strip<64, 1>(sp, bufA, Wf2, bufB, al_s, al_d, N, lane);
  }
  __threadfence();
  grid.sync();

  // ================= P6: layer-2 agg + bias + LayerNorm -> out =============
  for (int node = gw; node < N; node += nw) {
    int q = lane >> 4;
    int l = lane & 15;
    int dg = deg[node];
    int cnt = dg < CAP ? dg : CAP;
    float ald = al_d[node];
    float als = al_s[node];
    float wd = wedot[8];
    ushort4 bvS = ((const ushort4*)(bufB + (size_t)node * 64))[l];

    float4 acc = make_float4(0.f, 0.f, 0.f, 0.f);
    float den = 0.f;
    float easum = 0.f;

    for (int i = 0; i < cnt; i += 4) {
      int base = __builtin_amdgcn_readfirstlane(node * CAP + i);
      int2 r0 = ebuf[base], r1 = ebuf[base + 1], r2 = ebuf[base + 2], r3 = ebuf[base + 3];
      int2 rm = (q == 0) ? r0 : (q == 1) ? r1 : (q == 2) ? r2 : r3;
      bool valid = (i + q) < cnt;
      int src = valid ? rm.x : 0;
      float ev = valid ? __int_as_float(rm.y) : 0.f;
      easum += ev;
      float a = al_s[src] + ald + ev * wd;
      a = fmaxf(a, 0.2f * a);
      a = fminf(a, 30.f);
      float wv = __expf(a);
      wv = valid ? wv : 0.f;
      ushort4 bv = ((const ushort4*)(bufB + (size_t)src * 64))[l];
      den += wv;
      acc.x = fmaf(wv, bf2f(bv.x), acc.x);
      acc.y = fmaf(wv, bf2f(bv.y), acc.y);
      acc.z = fmaf(wv, bf2f(bv.z), acc.z);
      acc.w = fmaf(wv, bf2f(bv.w), acc.w);
    }

    den += __shfl_xor(den, 32, 64);
    den += __shfl_xor(den, 16, 64);
    easum += __shfl_xor(easum, 32, 64);
    easum += __shfl_xor(easum, 16, 64);
    acc.x += __shfl_xor(acc.x, 32, 64);
    acc.y += __shfl_xor(acc.y, 32, 64);
    acc.z += __shfl_xor(acc.z, 32, 64);
    acc.w += __shfl_xor(acc.w, 32, 64);
    acc.x += __shfl_xor(acc.x, 16, 64);
    acc.y += __shfl_xor(acc.y, 16, 64);
    acc.z += __shfl_xor(acc.z, 16, 64);
    acc.w += __shfl_xor(acc.w, 16, 64);

    {  // self loop post-reduce
      float evs = easum / fmaxf((float)dg, 1.f);
      float a = als + ald + evs * wd;
      a = fmaxf(a, 0.2f * a);
      a = fminf(a, 30.f);
      float wv = __expf(a);
      den += wv;
      acc.x = fmaf(wv, bf2f(bvS.x), acc.x);
      acc.y = fmaf(wv, bf2f(bvS.y), acc.y);
      acc.z = fmaf(wv, bf2f(bvS.z), acc.z);
      acc.w = fmaf(wv, bf2f(bvS.w), acc.w);
    }

    float inv = 1.f / (den + 1e-16f);
    float4 b4 = ((const float4*)b2)[l];
    float4 o;
    o.x = acc.x * inv + b4.x;
    o.y = acc.y * inv + b4.y;
    o.z = acc.z * inv + b4.z;
    o.w = acc.w * inv + b4.w;
    float s = (o.x + o.y) + (o.z + o.w);
#pragma unroll
    for (int off = 1; off < 16; off <<= 1) s += __shfl_xor(s, off, 64);
    float mu = s * (1.f / 64.f);
    float dx = o.x - mu, dy = o.y - mu, dz = o.z - mu, dw = o.w - mu;
    float v = (dx * dx + dy * dy) + (dz * dz + dw * dw);
#pragma unroll
    for (int off = 1; off < 16; off <<= 1) v += __shfl_xor(v, off, 64);
    float rs = rsqrtf(v * (1.f / 64.f) + 1e-5f);
    if (q == 0) {
      float4 g4 = ((const float4*)lng)[l];
      float4 lb4 = ((const float4*)lnb)[l];
      float4 rr;
      rr.x = dx * rs * g4.x + lb4.x;
      rr.y = dy * rs * g4.y + lb4.y;
      rr.z = dz * rs * g4.z + lb4.z;
      rr.w = dw * rs * g4.w + lb4.w;
      ((float4*)(outp + (size_t)node * 64))[l] = rr;
    }
  }
}

extern "C" void kernel_launch(void* const* d_in, const int* in_sizes, int n_in,
                              void* d_out, int out_size, void* d_ws, size_t ws_size,
                              hipStream_t stream) {
  const float* x = (const float*)d_in[0];
  const int* ei = (const int*)d_in[1];
  const float* eattr = (const float*)d_in[2];
  const float* W0 = (const float*)d_in[3];
  const float* as0 = (const float*)d_in[4];
  const float* ad0 = (const float*)d_in[5];
  const float* We0 = (const float*)d_in[6];
  const float* ae0 = (const float*)d_in[7];
  const float* b0 = (const float*)d_in[8];
  const float* W1 = (const float*)d_in[9];
  const float* as1 = (const float*)d_in[10];
  const float* ad1 = (const float*)d_in[11];
  const float* We1 = (const float*)d_in[12];
  const float* ae1 = (const float*)d_in[13];
  const float* b1 = (const float*)d_in[14];
  const float* W2 = (const float*)d_in[15];
  const float* as2 = (const float*)d_in[16];
  const float* ad2 = (const float*)d_in[17];
  const float* We2 = (const float*)d_in[18];
  const float* ae2 = (const float*)d_in[19];
  const float* b2 = (const float*)d_in[20];
  const float* lng = (const float*)d_in[21];
  const float* lnb = (const float*)d_in[22];
  float* outp = (float*)d_out;

  const int N = in_sizes[0] / 16;
  const int E = in_sizes[1] / 2;
  const int* srcv = ei;
  const int* dstv = ei + E;

  char* w = (char*)d_ws;
  size_t off = 0;
  auto alloc = [&](size_t bytes) -> void* {
    void* p = w + off;
    off += (bytes + 255) & ~(size_t)255;
    return p;
  };
  int* deg = (int*)alloc((size_t)N * 4);
  int2* ebuf = (int2*)alloc(((size_t)N * CAP + 8) * 8);  // +8: s_load overread pad
  float* wedot = (float*)alloc(16 * 4);
  float* al_s = (float*)alloc((size_t)N * 4 * 4);
  float* al_d = (float*)alloc((size_t)N * 4 * 4);
  unsigned short* Wf1 = (unsigned short*)alloc((size_t)17 * 4096 * 2);
  unsigned short* Wf2 = (unsigned short*)alloc((size_t)5 * 4096 * 2);
  unsigned short* bufA = (unsigned short*)alloc((size_t)N * 256 * 2);
  unsigned short* bufB = (unsigned short*)alloc((size_t)N * 256 * 2);
  (void)ws_size;

  static int coopBlocks = 0;
  if (coopBlocks == 0) {
    int dev = 0;
    hipGetDevice(&dev);
    hipDeviceProp_t prop;
    int cus = 256;
    if (hipGetDeviceProperties(&prop, dev) == hipSuccess) cus = prop.multiProcessorCount;
    int maxB = 0;
    hipOccupancyMaxActiveBlocksPerMultiprocessor(&maxB, (const void*)mega_kernel, 256, 0);
    if (maxB < 1) maxB = 1;
    if (maxB > 8) maxB = 8;
    coopBlocks = maxB * cus;
    if (coopBlocks < 64) coopBlocks = 64;
  }

  int Nv = N, Ev = E;
  void* args[] = {
      (void*)&x, (void*)&srcv, (void*)&dstv, (void*)&eattr,
      (void*)&W0, (void*)&as0, (void*)&ad0, (void*)&We0, (void*)&ae0, (void*)&b0,
      (void*)&W1, (void*)&as1, (void*)&ad1, (void*)&We1, (void*)&ae1, (void*)&b1,
      (void*)&W2, (void*)&as2, (void*)&ad2, (void*)&We2, (void*)&ae2, (void*)&b2,
      (void*)&lng, (void*)&lnb,
      (void*)&Wf1, (void*)&Wf2, (void*)&wedot, (void*)&al_s, (void*)&al_d,
      (void*)&deg, (void*)&ebuf, (void*)&bufA, (void*)&bufB, (void*)&outp,
      (void*)&Nv, (void*)&Ev};

  hipLaunchCooperativeKernel((const void*)mega_kernel, dim3(coopBlocks), dim3(256),
                             args, 0, stream);
}

// Round 4
// 214.563 us; speedup vs baseline: 4.4435x; 4.4435x over previous
//
#include <hip/hip_runtime.h>
#include <hip/hip_bf16.h>
#include <math.h>

// GAT x3 + LayerNorm for MI355X (gfx950).
// R15: REVERT R14's cooperative mega-kernel (cg grid.sync costs O(100us) per
// barrier on ROCm -> 953us). Back to R13 multi-dispatch, then fuse the two
// MFMA GEMMs into the aggregation kernels that produce their inputs:
// fused0 = agg0 + project + gemm1, fused1 = agg4 + gemm2. Blocks own 16-node
// tiles (4 waves x 4 nodes); per-node h rows go to LDS (528B padded stride);
// after __syncthreads the block MFMA-projects the 16-row tile (tiles split
// across waves) writing the next gather buffer + al dots. Deletes 2
// dispatches and the bufA round trip (~40 MB of L2 traffic). Per-layer al
// arrays (al0/al1/al2) since producer/consumer now share a dispatch.
// Carried (R12/R13): bucketed scatter CSR (CAP=64) in k1, inline softmax
// weights, easum-based analytic self-loop, bf16 h, al = A @ va via extra
// MFMA col-tile, layer-0 aggregate-then-project, scalar s_load edge records.

typedef __attribute__((ext_vector_type(8))) short short8;
typedef __attribute__((ext_vector_type(4))) float float4v;

#define CAP 64

__device__ __forceinline__ float wave_sum(float v) {
#pragma unroll
  for (int off = 32; off > 0; off >>= 1) v += __shfl_xor(v, off, 64);
  return v;
}

__device__ __forceinline__ unsigned short f2bf(float v) {
  unsigned u = __float_as_uint(v);
  unsigned r = u + 0x7fff + ((u >> 16) & 1);  // RNE
  return (unsigned short)(r >> 16);
}

__device__ __forceinline__ float bf2f(unsigned short u) {
  return __uint_as_float(((unsigned)u) << 16);
}

// ---------------- K1 mega-dispatch ----------------
// blocks [0,272): Wf1 tiles; [272,352): Wf2 tiles; 352: wedot;
// [353,353+gD): layer-0 al dots; rest: degree count + bucket scatter.
__global__ __launch_bounds__(256) void k1_kernel(
    const float* __restrict__ x, const int* __restrict__ srcv, const int* __restrict__ dstv,
    const float* __restrict__ eattr,
    const float* __restrict__ W0, const float* __restrict__ as0, const float* __restrict__ ad0,
    const float* __restrict__ We0, const float* __restrict__ ae0,
    const float* __restrict__ W1, const float* __restrict__ as1, const float* __restrict__ ad1,
    const float* __restrict__ We1, const float* __restrict__ ae1,
    const float* __restrict__ W2, const float* __restrict__ as2, const float* __restrict__ ad2,
    const float* __restrict__ We2, const float* __restrict__ ae2,
    unsigned short* __restrict__ Wf1, unsigned short* __restrict__ Wf2,
    float* __restrict__ wedot, float* __restrict__ al0s, float* __restrict__ al0d,
    int* __restrict__ deg, int2* __restrict__ ebuf,
    int N, int E, int gD) {
  int b = blockIdx.x;
  int tid = threadIdx.x;
  if (b < 272) {  // Wf1: 16 W1-tiles + 1 va1 tile, bf16 fragment order
    int idx = b * 256 + tid;
    int j = idx & 7, lane = (idx >> 3) & 63, ks = (idx >> 9) & 7, nt = idx >> 12;
    int k = ks * 32 + (lane >> 4) * 8 + j;
    int col = lane & 15;
    float v = 0.f;
    if (nt < 16) {
      v = W1[(size_t)k * 256 + nt * 16 + col];
    } else if (col < 4) {
      for (int c = 0; c < 64; c++) v = fmaf(W1[(size_t)k * 256 + col * 64 + c], as1[col * 64 + c], v);
    } else if (col < 8) {
      int h = col - 4;
      for (int c = 0; c < 64; c++) v = fmaf(W1[(size_t)k * 256 + h * 64 + c], ad1[h * 64 + c], v);
    }
    Wf1[idx] = f2bf(v);
  } else if (b < 352) {  // Wf2: 4 W2-tiles + 1 va2 tile
    int idx = (b - 272) * 256 + tid;
    int j = idx & 7, lane = (idx >> 3) & 63, ks = (idx >> 9) & 7, nt = idx >> 12;
    int k = ks * 32 + (lane >> 4) * 8 + j;
    int col = lane & 15;
    float v = 0.f;
    if (nt < 4) {
      v = W2[(size_t)k * 64 + nt * 16 + col];
    } else if (col < 1) {
      for (int c = 0; c < 64; c++) v = fmaf(W2[(size_t)k * 64 + c], as2[c], v);
    } else if (col < 2) {
      for (int c = 0; c < 64; c++) v = fmaf(W2[(size_t)k * 64 + c], ad2[c], v);
    }
    Wf2[idx] = f2bf(v);
  } else if (b == 352) {  // wedot
    if (tid >= 64) return;
    int c = tid;
    for (int h = 0; h < 4; h++) {
      float v = wave_sum(We0[h * 64 + c] * ae0[h * 64 + c]);
      if (c == 0) wedot[h] = v;
    }
    for (int h = 0; h < 4; h++) {
      float v = wave_sum(We1[h * 64 + c] * ae1[h * 64 + c]);
      if (c == 0) wedot[4 + h] = v;
    }
    float v = wave_sum(We2[c] * ae2[c]);
    if (c == 0) wedot[8] = v;
  } else if (b < 353 + gD) {  // layer-0 dots: al = x @ va0
    __shared__ float va[128];
    if (tid < 128) {
      int k = tid >> 3, col = tid & 7;
      float v = 0.f;
      if (col < 4) {
        for (int c = 0; c < 64; c++) v = fmaf(W0[(size_t)k * 256 + col * 64 + c], as0[col * 64 + c], v);
      } else {
        int h = col - 4;
        for (int c = 0; c < 64; c++) v = fmaf(W0[(size_t)k * 256 + h * 64 + c], ad0[h * 64 + c], v);
      }
      va[tid] = v;
    }
    __syncthreads();
    int node = (b - 353) * 256 + tid;
    if (node >= N) return;
    const float4* xr = (const float4*)(x + (size_t)node * 16);
    float4 xv[4];
#pragma unroll
    for (int q = 0; q < 4; q++) xv[q] = xr[q];
    float al[8];
#pragma unroll
    for (int j = 0; j < 8; j++) al[j] = 0.f;
#pragma unroll
    for (int k = 0; k < 16; k++) {
      float xk = ((const float*)xv)[k];
#pragma unroll
      for (int j = 0; j < 8; j++) al[j] = fmaf(xk, va[k * 8 + j], al[j]);
    }
    ((float4*)al0s)[node] = make_float4(al[0], al[1], al[2], al[3]);
    ((float4*)al0d)[node] = make_float4(al[4], al[5], al[6], al[7]);
  } else {  // degree count + bucket scatter (this IS the CSR fill)
    int e = (b - 353 - gD) * 256 + tid;
    if (e >= E) return;
    int d = dstv[e];
    int s = srcv[e];
    float ea = eattr[e];
    int pos = atomicAdd(&deg[d], 1);
    if (pos < CAP) ebuf[(size_t)d * CAP + pos] = make_int2(s, __float_as_int(ea));
  }
}

// fused0: layer-0 aggregate + project 16->256 (per node, in-wave) -> LDS row,
// then block-level 16-row MFMA gemm1 (K=256, 16 out tiles + va tile) ->
// buf256 + al1s/al1d. Block = 4 waves x 4 nodes = 16-node tile.
__global__ __launch_bounds__(256) void fused0_kernel(
    const int* __restrict__ deg, const int2* __restrict__ ebuf,
    const float* __restrict__ al0s, const float* __restrict__ al0d,
    const float* __restrict__ wedot,
    const float* __restrict__ x, const float* __restrict__ W0,
    const float* __restrict__ b0, const unsigned short* __restrict__ Wf1,
    unsigned short* __restrict__ buf256, float* __restrict__ al1s,
    float* __restrict__ al1d, int n) {
  __shared__ unsigned short hrow[16][264];  // 528B row stride (bank-stagger)
  int tile = blockIdx.x;
  int wv = threadIdx.x >> 6;
  int lane = threadIdx.x & 63;
  int es = lane >> 4;
  int c = lane & 15;

  for (int s = 0; s < 4; s++) {
    int r = wv * 4 + s;
    int node = tile * 16 + r;
    if (node < n) {
      int dg = deg[node];
      int cnt = dg < CAP ? dg : CAP;
      float xself = x[(size_t)node * 16 + c];
      float4 as4s = ((const float4*)al0s)[node];
      float4 ald = ((const float4*)al0d)[node];
      float wd[4];
#pragma unroll
      for (int h = 0; h < 4; h++) wd[h] = wedot[h];

      float Z[4] = {0.f, 0.f, 0.f, 0.f};
      float den[4] = {0.f, 0.f, 0.f, 0.f};
      float easum = 0.f;

      for (int i = 0; i < cnt; i += 4) {
        int base = __builtin_amdgcn_readfirstlane(node * CAP + i);
        int2 r0 = ebuf[base], r1 = ebuf[base + 1], r2 = ebuf[base + 2], r3 = ebuf[base + 3];
        int2 rm = (es == 0) ? r0 : (es == 1) ? r1 : (es == 2) ? r2 : r3;
        bool valid = (i + es) < cnt;
        int src = valid ? rm.x : 0;
        float ev = valid ? __int_as_float(rm.y) : 0.f;
        float xv = x[(size_t)src * 16 + c];
        float4 as4 = ((const float4*)al0s)[src];
        easum += ev;
#pragma unroll
        for (int h = 0; h < 4; h++) {
          float a = ((const float*)&as4)[h] + ((const float*)&ald)[h] + ev * wd[h];
          a = fmaxf(a, 0.2f * a);
          a = fminf(a, 30.f);
          float wvv = __expf(a);
          wvv = valid ? wvv : 0.f;
          den[h] += wvv;
          Z[h] = fmaf(wvv, xv, Z[h]);
        }
      }

#pragma unroll
      for (int h = 0; h < 4; h++) {
        Z[h] += __shfl_xor(Z[h], 16, 64);
        Z[h] += __shfl_xor(Z[h], 32, 64);
        den[h] += __shfl_xor(den[h], 16, 64);
        den[h] += __shfl_xor(den[h], 32, 64);
      }
      easum += __shfl_xor(easum, 16, 64);
      easum += __shfl_xor(easum, 32, 64);

      {  // self loop post-reduce
        float evs = easum / fmaxf((float)dg, 1.f);
#pragma unroll
        for (int h = 0; h < 4; h++) {
          float a = ((const float*)&as4s)[h] + ((const float*)&ald)[h] + evs * wd[h];
          a = fmaxf(a, 0.2f * a);
          a = fminf(a, 30.f);
          float wvv = __expf(a);
          den[h] += wvv;
          Z[h] = fmaf(wvv, xself, Z[h]);
        }
      }

      int h = es;
      float zsel = (h == 0) ? Z[0] : (h == 1) ? Z[1] : (h == 2) ? Z[2] : Z[3];
      float dsel = (h == 0) ? den[0] : (h == 1) ? den[1] : (h == 2) ? den[2] : den[3];
      float zn = zsel / (dsel + 1e-16f);
      float4 w0r[16];
#pragma unroll
      for (int cc = 0; cc < 16; cc++) w0r[cc] = ((const float4*)(W0 + (size_t)cc * 256))[lane];
      float zc[16];
      int basel = lane & 48;
#pragma unroll
      for (int cc = 0; cc < 16; cc++) zc[cc] = __shfl(zn, basel + cc, 64);
      float o[4];
      float4 b4 = ((const float4*)b0)[lane];
#pragma unroll
      for (int jj = 0; jj < 4; jj++) o[jj] = ((const float*)&b4)[jj];
#pragma unroll
      for (int cc = 0; cc < 16; cc++) {
#pragma unroll
        for (int jj = 0; jj < 4; jj++) o[jj] = fmaf(zc[cc], ((const float*)&w0r[cc])[jj], o[jj]);
      }
      ushort4 o4;
      float ox = o[0] > 0.f ? o[0] : expm1f(o[0]);
      float oy = o[1] > 0.f ? o[1] : expm1f(o[1]);
      float oz = o[2] > 0.f ? o[2] : expm1f(o[2]);
      float ow = o[3] > 0.f ? o[3] : expm1f(o[3]);
      o4.x = f2bf(ox);
      o4.y = f2bf(oy);
      o4.z = f2bf(oz);
      o4.w = f2bf(ow);
      *(ushort4*)&hrow[r][lane * 4] = o4;
    } else {
      *(ushort4*)&hrow[r][lane * 4] = make_ushort4(0, 0, 0, 0);
    }
  }
  __syncthreads();

  // ---- block-level gemm1 over the 16-row LDS tile
  int m = lane & 15, q = lane >> 4;
  int row0 = tile * 16;
  short8 afrag[8];
#pragma unroll
  for (int ks = 0; ks < 8; ks++) afrag[ks] = *(short8*)&hrow[m][ks * 32 + q * 8];

  const short8* wf = (const short8*)Wf1;
  for (int nt = wv; nt < 17; nt += 4) {
    const short8* bl = wf + (size_t)nt * 8 * 64 + lane;
    short8 bf[8];
#pragma unroll
    for (int ks = 0; ks < 8; ks++) bf[ks] = bl[ks * 64];
    float4v acc = {0.f, 0.f, 0.f, 0.f};
#pragma unroll
    for (int ks = 0; ks < 8; ks++)
      acc = __builtin_amdgcn_mfma_f32_16x16x32_bf16(afrag[ks], bf[ks], acc, 0, 0, 0);
    if (nt < 16) {
      int col = nt * 16 + m;
#pragma unroll
      for (int reg = 0; reg < 4; reg++) {
        int rr = row0 + q * 4 + reg;
        if (rr < n) buf256[(size_t)rr * 256 + col] = f2bf(acc[reg]);
      }
    } else {
#pragma unroll
      for (int reg = 0; reg < 4; reg++) {
        int rr = row0 + q * 4 + reg;
        if (rr < n) {
          if (m < 4) al1s[(size_t)rr * 4 + m] = acc[reg];
          else if (m < 8) al1d[(size_t)rr * 4 + (m - 4)] = acc[reg];
        }
      }
    }
  }
}

// fused1: layer-1 aggregation (H=4, inline weights) -> LDS row, then
// block-level 16-row MFMA gemm2 (K=256, 4 out tiles + va tile) ->
// buf64 + al2s/al2d. Block = 4 waves x 4 nodes = 16-node tile.
__global__ __launch_bounds__(256) void fused1_kernel(
    const int* __restrict__ deg, const int2* __restrict__ ebuf,
    const float* __restrict__ al1s, const float* __restrict__ al1d,
    const float* __restrict__ wedot,
    const unsigned short* __restrict__ buf256, const float* __restrict__ b1,
    const unsigned short* __restrict__ Wf2, unsigned short* __restrict__ buf64,
    float* __restrict__ al2s, float* __restrict__ al2d, int n) {
  __shared__ unsigned short hrow[16][264];  // 528B row stride
  int tile = blockIdx.x;
  int wv = threadIdx.x >> 6;
  int lane = threadIdx.x & 63;
  int half = lane >> 5;
  int l = lane & 31;
  int h4 = l >> 3;

  for (int s = 0; s < 4; s++) {
    int r = wv * 4 + s;
    int node = tile * 16 + r;
    if (node < n) {
      int dg = deg[node];
      int cnt = dg < CAP ? dg : CAP;
      float aldh = al1d[(size_t)node * 4 + h4];
      float alsh = al1s[(size_t)node * 4 + h4];
      float wdh = wedot[4 + h4];
      short8 rowS = ((const short8*)(buf256 + (size_t)node * 256))[l];

      float acc[8];
#pragma unroll
      for (int j = 0; j < 8; j++) acc[j] = 0.f;
      float den = 0.f;
      float easum = 0.f;

      for (int i = 0; i < cnt; i += 4) {
        int base = __builtin_amdgcn_readfirstlane(node * CAP + i);
        int2 r0 = ebuf[base], r1 = ebuf[base + 1], r2 = ebuf[base + 2], r3 = ebuf[base + 3];
        bool vA = (i + (half ? 1 : 0)) < cnt;
        bool vB = (i + (half ? 3 : 2)) < cnt;
        int2 rA = half ? r1 : r0;
        int2 rB = half ? r3 : r2;
        int srcA = vA ? rA.x : 0;
        int srcB = vB ? rB.x : 0;
        float evA = vA ? __int_as_float(rA.y) : 0.f;
        float evB = vB ? __int_as_float(rB.y) : 0.f;
        easum += evA + evB;
        float aA = al1s[(size_t)srcA * 4 + h4] + aldh + evA * wdh;
        float aB = al1s[(size_t)srcB * 4 + h4] + aldh + evB * wdh;
        aA = fmaxf(aA, 0.2f * aA);
        aB = fmaxf(aB, 0.2f * aB);
        aA = fminf(aA, 30.f);
        aB = fminf(aB, 30.f);
        float wA = __expf(aA);
        float wB = __expf(aB);
        wA = vA ? wA : 0.f;
        wB = vB ? wB : 0.f;
        short8 rowA = ((const short8*)(buf256 + (size_t)srcA * 256))[l];
        short8 rowB = ((const short8*)(buf256 + (size_t)srcB * 256))[l];
        den += wA + wB;
        const unsigned short* pa = (const unsigned short*)&rowA;
        const unsigned short* pb = (const unsigned short*)&rowB;
#pragma unroll
        for (int j = 0; j < 8; j++) acc[j] = fmaf(wA, bf2f(pa[j]), acc[j]);
#pragma unroll
        for (int j = 0; j < 8; j++) acc[j] = fmaf(wB, bf2f(pb[j]), acc[j]);
      }

      den += __shfl_xor(den, 32, 64);
      easum += __shfl_xor(easum, 32, 64);
#pragma unroll
      for (int j = 0; j < 8; j++) acc[j] += __shfl_xor(acc[j], 32, 64);

      {  // self loop post-reduce
        float evs = easum / fmaxf((float)dg, 1.f);
        float a = alsh + aldh + evs * wdh;
        a = fmaxf(a, 0.2f * a);
        a = fminf(a, 30.f);
        float wvv = __expf(a);
        const unsigned short* ps = (const unsigned short*)&rowS;
        den += wvv;
#pragma unroll
        for (int j = 0; j < 8; j++) acc[j] = fmaf(wvv, bf2f(ps[j]), acc[j]);
      }

      if (half == 0) {
        float inv = 1.f / (den + 1e-16f);
        float4 bb0 = ((const float4*)b1)[l * 2];
        float4 bb1 = ((const float4*)b1)[l * 2 + 1];
        unsigned short o8[8];
#pragma unroll
        for (int j = 0; j < 8; j++) {
          float bjv = (j < 4) ? ((const float*)&bb0)[j] : ((const float*)&bb1)[j - 4];
          float o = acc[j] * inv + bjv;
          o = o > 0.f ? o : expm1f(o);
          o8[j] = f2bf(o);
        }
        *(short8*)&hrow[r][l * 8] = *(short8*)o8;
      }
    } else if (half == 0) {
      unsigned short z8[8] = {0, 0, 0, 0, 0, 0, 0, 0};
      *(short8*)&hrow[r][l * 8] = *(short8*)z8;
    }
  }
  __syncthreads();

  // ---- block-level gemm2 over the 16-row LDS tile
  int m = lane & 15, q = lane >> 4;
  int row0 = tile * 16;
  short8 afrag[8];
#pragma unroll
  for (int ks = 0; ks < 8; ks++) afrag[ks] = *(short8*)&hrow[m][ks * 32 + q * 8];

  const short8* wf = (const short8*)Wf2;
  for (int nt = wv; nt < 5; nt += 4) {
    const short8* bl = wf + (size_t)nt * 8 * 64 + lane;
    short8 bf[8];
#pragma unroll
    for (int ks = 0; ks < 8; ks++) bf[ks] = bl[ks * 64];
    float4v acc = {0.f, 0.f, 0.f, 0.f};
#pragma unroll
    for (int ks = 0; ks < 8; ks++)
      acc = __builtin_amdgcn_mfma_f32_16x16x32_bf16(afrag[ks], bf[ks], acc, 0, 0, 0);
    if (nt < 4) {
      int col = nt * 16 + m;
#pragma unroll
      for (int reg = 0; reg < 4; reg++) {
        int rr = row0 + q * 4 + reg;
        if (rr < n) buf64[(size_t)rr * 64 + col] = f2bf(acc[reg]);
      }
    } else {
#pragma unroll
      for (int reg = 0; reg < 4; reg++) {
        int rr = row0 + q * 4 + reg;
        if (rr < n) {
          if (m < 1) al2s[rr] = acc[reg];
          else if (m < 2) al2d[rr] = acc[reg];
        }
      }
    }
  }
}

// H=1 aggregation + inline weights + bias + LayerNorm: one wave per node;
// quad q takes edge q; records via SCALAR s_load; self-loop post-reduction.
__global__ __launch_bounds__(256) void agg_ln_kernel(
    const int* __restrict__ deg, const int2* __restrict__ ebuf,
    const float* __restrict__ al2s, const float* __restrict__ al2d,
    const float* __restrict__ wedot,
    const unsigned short* __restrict__ B, const float* __restrict__ bias,
    const float* __restrict__ ln_g, const float* __restrict__ ln_b,
    float* __restrict__ out, int n) {
  int node = blockIdx.x * 4 + (threadIdx.x >> 6);
  if (node >= n) return;
  int lane = threadIdx.x & 63;
  int q = lane >> 4;
  int l = lane & 15;
  int dg = deg[node];
  int cnt = dg < CAP ? dg : CAP;
  float ald = al2d[node];
  float als = al2s[node];
  float wd = wedot[0];
  ushort4 bvS = ((const ushort4*)(B + (size_t)node * 64))[l];

  float4 acc = make_float4(0.f, 0.f, 0.f, 0.f);
  float den = 0.f;
  float easum = 0.f;

  for (int i = 0; i < cnt; i += 4) {
    int base = __builtin_amdgcn_readfirstlane(node * CAP + i);
    int2 r0 = ebuf[base], r1 = ebuf[base + 1], r2 = ebuf[base + 2], r3 = ebuf[base + 3];
    int2 rm = (q == 0) ? r0 : (q == 1) ? r1 : (q == 2) ? r2 : r3;
    bool valid = (i + q) < cnt;
    int src = valid ? rm.x : 0;
    float ev = valid ? __int_as_float(rm.y) : 0.f;
    easum += ev;
    float a = al2s[src] + ald + ev * wd;
    a = fmaxf(a, 0.2f * a);
    a = fminf(a, 30.f);
    float wv = __expf(a);
    wv = valid ? wv : 0.f;
    ushort4 bv = ((const ushort4*)(B + (size_t)src * 64))[l];
    den += wv;
    acc.x = fmaf(wv, bf2f(bv.x), acc.x);
    acc.y = fmaf(wv, bf2f(bv.y), acc.y);
    acc.z = fmaf(wv, bf2f(bv.z), acc.z);
    acc.w = fmaf(wv, bf2f(bv.w), acc.w);
  }

  den += __shfl_xor(den, 32, 64);
  den += __shfl_xor(den, 16, 64);
  easum += __shfl_xor(easum, 32, 64);
  easum += __shfl_xor(easum, 16, 64);
  acc.x += __shfl_xor(acc.x, 32, 64);
  acc.y += __shfl_xor(acc.y, 32, 64);
  acc.z += __shfl_xor(acc.z, 32, 64);
  acc.w += __shfl_xor(acc.w, 32, 64);
  acc.x += __shfl_xor(acc.x, 16, 64);
  acc.y += __shfl_xor(acc.y, 16, 64);
  acc.z += __shfl_xor(acc.z, 16, 64);
  acc.w += __shfl_xor(acc.w, 16, 64);

  {  // self loop post-reduce
    float evs = easum / fmaxf((float)dg, 1.f);
    float a = als + ald + evs * wd;
    a = fmaxf(a, 0.2f * a);
    a = fminf(a, 30.f);
    float wv = __expf(a);
    den += wv;
    acc.x = fmaf(wv, bf2f(bvS.x), acc.x);
    acc.y = fmaf(wv, bf2f(bvS.y), acc.y);
    acc.z = fmaf(wv, bf2f(bvS.z), acc.z);
    acc.w = fmaf(wv, bf2f(bvS.w), acc.w);
  }

  float inv = 1.f / (den + 1e-16f);
  float4 b4 = ((const float4*)bias)[l];
  float4 o;
  o.x = acc.x * inv + b4.x;
  o.y = acc.y * inv + b4.y;
  o.z = acc.z * inv + b4.z;
  o.w = acc.w * inv + b4.w;
  float s = (o.x + o.y) + (o.z + o.w);
#pragma unroll
  for (int off = 1; off < 16; off <<= 1) s += __shfl_xor(s, off, 64);
  float mu = s * (1.f / 64.f);
  float dx = o.x - mu, dy = o.y - mu, dz = o.z - mu, dw = o.w - mu;
  float v = (dx * dx + dy * dy) + (dz * dz + dw * dw);
#pragma unroll
  for (int off = 1; off < 16; off <<= 1) v += __shfl_xor(v, off, 64);
  float rs = rsqrtf(v * (1.f / 64.f) + 1e-5f);
  if (q == 0) {
    float4 g4 = ((const float4*)ln_g)[l];
    float4 lb4 = ((const float4*)ln_b)[l];
    float4 rr;
    rr.x = dx * rs * g4.x + lb4.x;
    rr.y = dy * rs * g4.y + lb4.y;
    rr.z = dz * rs * g4.z + lb4.z;
    rr.w = dw * rs * g4.w + lb4.w;
    ((float4*)(out + (size_t)node * 64))[l] = rr;
  }
}

extern "C" void kernel_launch(void* const* d_in, const int* in_sizes, int n_in,
                              void* d_out, int out_size, void* d_ws, size_t ws_size,
                              hipStream_t stream) {
  const float* x = (const float*)d_in[0];
  const int* ei = (const int*)d_in[1];
  const float* eattr = (const float*)d_in[2];
  const float* W0 = (const float*)d_in[3];
  const float* as0 = (const float*)d_in[4];
  const float* ad0 = (const float*)d_in[5];
  const float* We0 = (const float*)d_in[6];
  const float* ae0 = (const float*)d_in[7];
  const float* b0 = (const float*)d_in[8];
  const float* W1 = (const float*)d_in[9];
  const float* as1 = (const float*)d_in[10];
  const float* ad1 = (const float*)d_in[11];
  const float* We1 = (const float*)d_in[12];
  const float* ae1 = (const float*)d_in[13];
  const float* b1 = (const float*)d_in[14];
  const float* W2 = (const float*)d_in[15];
  const float* as2 = (const float*)d_in[16];
  const float* ad2 = (const float*)d_in[17];
  const float* We2 = (const float*)d_in[18];
  const float* ae2 = (const float*)d_in[19];
  const float* b2 = (const float*)d_in[20];
  const float* lng = (const float*)d_in[21];
  const float* lnb = (const float*)d_in[22];
  float* outp = (float*)d_out;

  const int N = in_sizes[0] / 16;
  const int E = in_sizes[1] / 2;
  const int* srcv = ei;
  const int* dstv = ei + E;

  char* w = (char*)d_ws;
  size_t off = 0;
  auto alloc = [&](size_t bytes) -> void* {
    void* p = w + off;
    off += (bytes + 255) & ~(size_t)255;
    return p;
  };
  int* deg = (int*)alloc((size_t)N * 4);
  size_t zero_bytes = off;  // deg must start at 0
  int2* ebuf = (int2*)alloc(((size_t)N * CAP + 8) * 8);  // +8: s_load overread pad
  float* wedot = (float*)alloc(16 * 4);
  float* al0s = (float*)alloc((size_t)N * 4 * 4);
  float* al0d = (float*)alloc((size_t)N * 4 * 4);
  float* al1s = (float*)alloc((size_t)N * 4 * 4);
  float* al1d = (float*)alloc((size_t)N * 4 * 4);
  float* al2s = (float*)alloc((size_t)N * 4);
  float* al2d = (float*)alloc((size_t)N * 4);
  unsigned short* Wf1 = (unsigned short*)alloc((size_t)17 * 4096 * 2);
  unsigned short* Wf2 = (unsigned short*)alloc((size_t)5 * 4096 * 2);
  unsigned short* buf256 = (unsigned short*)alloc((size_t)N * 256 * 2);
  unsigned short* buf64 = (unsigned short*)alloc((size_t)N * 64 * 2);
  (void)ws_size;

  hipMemsetAsync(d_ws, 0, zero_bytes, stream);

  int gE = (E + 255) / 256;
  int gD = (N + 255) / 256;

  k1_kernel<<<353 + gD + gE, 256, 0, stream>>>(
      x, srcv, dstv, eattr, W0, as0, ad0, We0, ae0, W1, as1, ad1, We1, ae1,
      W2, as2, ad2, We2, ae2, Wf1, Wf2, wedot, al0s, al0d, deg, ebuf, N, E, gD);

  int gT = (N + 15) / 16;
  int gNode4 = (N + 3) / 4;

  // ---- layer 0 + gemm1 fused
  fused0_kernel<<<gT, 256, 0, stream>>>(deg, ebuf, al0s, al0d, wedot, x, W0, b0,
                                        Wf1, buf256, al1s, al1d, N);

  // ---- layer 1 + gemm2 fused
  fused1_kernel<<<gT, 256, 0, stream>>>(deg, ebuf, al1s, al1d, wedot, buf256, b1,
                                        Wf2, buf64, al2s, al2d, N);

  // ---- layer 2 (+ LayerNorm -> d_out)
  agg_ln_kernel<<<gNode4, 256, 0, stream>>>(deg, ebuf, al2s, al2d, wedot + 8,
                                            buf64, b2, lng, lnb, outp, N);
}